// Round 1
// 269.930 us; speedup vs baseline: 1.0286x; 1.0286x over previous
//
#include <hip/hip_runtime.h>
#include <hip/hip_bf16.h>

typedef __hip_bfloat16 bf16;
typedef __attribute__((ext_vector_type(8))) short s16x8;
typedef __attribute__((ext_vector_type(4))) float f32x4;

#define DEV __device__ __forceinline__

DEV float us2f(unsigned short u){ return __uint_as_float(((unsigned int)u) << 16); }
DEV unsigned short f2us(float f){
    __hip_bfloat16 h = __float2bfloat16(f);
    unsigned short r; __builtin_memcpy(&r, &h, 2); return r;
}
DEV unsigned pack2(float a, float b){ return (unsigned)f2us(a) | ((unsigned)f2us(b) << 16); }

template<bool F32> DEV float ldf(const void* p, long i){
    if (F32) return reinterpret_cast<const float*>(p)[i];
    return us2f(reinterpret_cast<const unsigned short*>(p)[i]);
}
template<bool F32> DEV unsigned short ld16(const void* p, long i){
    if (F32) return f2us(reinterpret_cast<const float*>(p)[i]);
    return reinterpret_cast<const unsigned short*>(p)[i];
}

union U16x8 { uint4 u; s16x8 v; };

// dtype flag: maskV[0]==1.0 always. bf16 -> ushort0 = 0x3F80; fp32 LE -> 0x0000.
DEV bool is_f32(const void* maskV){
    return reinterpret_cast<const unsigned short*>(maskV)[0] != 0x3F80;
}

// ---------------------------------------------------------------------------
// Kernel T: weight pre-transposes (coalesced reads, scattered stores).
// ---------------------------------------------------------------------------
template<bool F32>
DEV void wtrans_body(const void* Wm1, const void* Wm2, const void* Wm3,
                     const void* Wp, const void* Wd1, const void* Wd2,
                     unsigned short* wt1, unsigned short* wt2, unsigned short* wt3,
                     unsigned short* wpT, unsigned short* wd1T, unsigned short* wd2T,
                     long t)
{
    if (t < 61440) {                 // wt1[h][k] = Wm1[k][h], K padded to 480
        int k = (int)(t >> 7), h = (int)(t & 127);
        wt1[(long)h*480 + k] = (k < 456) ? ld16<F32>(Wm1, (long)k*128 + h) : (unsigned short)0;
    } else if (t < 77824) {
        long t2 = t - 61440; int k = (int)(t2 >> 7), h = (int)(t2 & 127);
        wt2[(long)h*128 + k] = ld16<F32>(Wm2, (long)k*128 + h);
    } else if (t < 94208) {
        long t2 = t - 77824; int k = (int)(t2 >> 7), h = (int)(t2 & 127);
        wt3[(long)h*128 + k] = ld16<F32>(Wm3, (long)k*128 + h);
    } else if (t < 97280) {
        long t2 = t - 94208; int i = (int)(t2 / 24), j = (int)(t2 % 24);
        wpT[(long)j*128 + i] = ld16<F32>(Wp, (long)i*24 + j);
    } else if (t < 162816) {         // wd1T[n][k] = Wd1[k][n]  (512 x 128)
        long t2 = t - 97280; int k = (int)(t2 >> 9), n = (int)(t2 & 511);
        wd1T[(long)n*128 + k] = ld16<F32>(Wd1, (long)k*512 + n);
    } else if (t < 228352) {         // wd2T[n][k] = Wd2[k][n]  (128 x 512)
        long t2 = t - 162816; int k = (int)(t2 >> 7), n = (int)(t2 & 127);
        wd2T[(long)n*512 + k] = ld16<F32>(Wd2, (long)k*128 + n);
    }
}

__global__ __launch_bounds__(256) void wtrans_k(
    const void* __restrict__ Wm1, const void* __restrict__ Wm2, const void* __restrict__ Wm3,
    const void* __restrict__ Wp, const void* __restrict__ Wd1, const void* __restrict__ Wd2,
    unsigned short* __restrict__ wt1, unsigned short* __restrict__ wt2,
    unsigned short* __restrict__ wt3, unsigned short* __restrict__ wpT,
    unsigned short* __restrict__ wd1T, unsigned short* __restrict__ wd2T,
    const void* __restrict__ maskV)
{
    long t = (long)blockIdx.x*256 + threadIdx.x;
    if (is_f32(maskV)) wtrans_body<true >(Wm1,Wm2,Wm3,Wp,Wd1,Wd2,wt1,wt2,wt3,wpT,wd1T,wd2T,t);
    else               wtrans_body<false>(Wm1,Wm2,Wm3,Wp,Wd1,Wd2,wt1,wt2,wt3,wpT,wd1T,wd2T,t);
}

// ---------------------------------------------------------------------------
// Kernel UV: per-node partial layer-1 products (hoisted out of the edge loop).
//   U'[n] = hV[n] @ Wm1[0:128,:]   + bm1   (own-node block, shared by 32 edges)
//   V [n] = hV[n] @ Wm1[256:384,:]         (neighbor block, gathered per edge)
//   16 rows/block, 128 threads: wave 0 -> U', wave 1 -> V. fp32 out.
// ---------------------------------------------------------------------------
template<bool F32>
DEV void uv_body(const void* hV, const void* bm1, const unsigned short* wt1,
                 float* Uw, float* Vw, int r0, int tid)
{
    const int lane = tid & 63, w = tid >> 6;
    const int lm = lane & 15, quad = lane >> 4;

    s16x8 af[4];
    #pragma unroll
    for (int kc=0; kc<4; ++kc) {
        long src = (long)(r0 + lm)*128 + kc*32 + quad*8;
        U16x8 pk;
        if (F32) {
            const float4* vp = reinterpret_cast<const float4*>(reinterpret_cast<const float*>(hV) + src);
            float4 x = vp[0], y = vp[1];
            pk.u.x = pack2(x.x,x.y); pk.u.y = pack2(x.z,x.w);
            pk.u.z = pack2(y.x,y.y); pk.u.w = pack2(y.z,y.w);
        } else {
            pk.u = *reinterpret_cast<const uint4*>(reinterpret_cast<const unsigned short*>(hV) + src);
        }
        af[kc] = pk.v;
    }

    const int koff = w ? 256 : 0;   // Wm1 k-slice: own hV (0..127) / nbr hV (256..383)
    f32x4 acc[8];
    #pragma unroll
    for (int nt=0; nt<8; ++nt) {
        float b0 = w ? 0.f : ldf<F32>(bm1, nt*16 + lm);
        f32x4 iv = {b0,b0,b0,b0};
        acc[nt] = iv;
    }
    #pragma unroll
    for (int kc=0; kc<4; ++kc) {
        #pragma unroll
        for (int nt=0; nt<8; ++nt) {
            s16x8 bf = *reinterpret_cast<const s16x8*>(wt1 + (long)(nt*16 + lm)*480 + koff + kc*32 + quad*8);
            acc[nt] = __builtin_amdgcn_mfma_f32_16x16x32_bf16(af[kc], bf, acc[nt], 0,0,0);
        }
    }
    float* out = w ? Vw : Uw;
    #pragma unroll
    for (int nt=0; nt<8; ++nt)
        #pragma unroll
        for (int r=0; r<4; ++r)
            out[(long)(r0 + quad*4 + r)*128 + nt*16 + lm] = acc[nt][r];
}

__global__ __launch_bounds__(128) void uv_k(
    const void* __restrict__ hV, const void* __restrict__ bm1,
    const unsigned short* __restrict__ wt1,
    float* __restrict__ Uw, float* __restrict__ Vw,
    const void* __restrict__ maskV)
{
    int r0 = blockIdx.x * 16, tid = threadIdx.x;
    if (is_f32(maskV)) uv_body<true >(hV, bm1, wt1, Uw, Vw, r0, tid);
    else               uv_body<false>(hV, bm1, wt1, Uw, Vw, r0, tid);
}

// ---------------------------------------------------------------------------
// Kernel A: per-node frames + local/global points + pl_norm -> fp32 workspace
// ---------------------------------------------------------------------------
struct PrepSmem { float sX[9], sR[9], st[3], spl[24], hvs[128]; };

template<bool F32>
DEV void prep_body(const void* hV, const void* X, const unsigned short* wpT, const void* bp,
                   float* pg, float* pl, float* pln, float* Rw, float* tw,
                   PrepSmem& s, int n, int tid)
{
    if (tid < 9) s.sX[tid] = ldf<F32>(X, (long)n*9 + tid);
    for (int i = tid; i < 128; i += 64) s.hvs[i] = ldf<F32>(hV, (long)n*128 + i);
    __syncthreads();

    if (tid == 0) {
        float Nx=s.sX[0],Ny=s.sX[1],Nz=s.sX[2];
        float Ax=s.sX[3],Ay=s.sX[4],Az=s.sX[5];
        float Cx=s.sX[6],Cy=s.sX[7],Cz=s.sX[8];
        float v1x=Cx-Ax, v1y=Cy-Ay, v1z=Cz-Az;
        float v2x=Nx-Ax, v2y=Ny-Ay, v2z=Nz-Az;
        float r1 = 1.f/sqrtf(v1x*v1x+v1y*v1y+v1z*v1z + 1e-8f);
        float e1x=v1x*r1, e1y=v1y*r1, e1z=v1z*r1;
        float dp = e1x*v2x+e1y*v2y+e1z*v2z;
        float u2x=v2x-e1x*dp, u2y=v2y-e1y*dp, u2z=v2z-e1z*dp;
        float r2 = 1.f/sqrtf(u2x*u2x+u2y*u2y+u2z*u2z + 1e-8f);
        float e2x=u2x*r2, e2y=u2y*r2, e2z=u2z*r2;
        float e3x = e1y*e2z - e1z*e2y;
        float e3y = e1z*e2x - e1x*e2z;
        float e3z = e1x*e2y - e1y*e2x;
        s.sR[0]=e1x; s.sR[1]=e2x; s.sR[2]=e3x;
        s.sR[3]=e1y; s.sR[4]=e2y; s.sR[5]=e3y;
        s.sR[6]=e1z; s.sR[7]=e2z; s.sR[8]=e3z;
        s.st[0]=Ax*0.1f; s.st[1]=Ay*0.1f; s.st[2]=Az*0.1f;
    }
    if (tid < 24) {
        float acc = ldf<F32>(bp, tid);
        const unsigned short* wr = wpT + (long)tid*128;
        #pragma unroll
        for (int c=0;c<16;c++){
            ushort4 w0 = *reinterpret_cast<const ushort4*>(wr + c*8);
            ushort4 w1 = *reinterpret_cast<const ushort4*>(wr + c*8 + 4);
            acc += s.hvs[c*8+0]*us2f(w0.x) + s.hvs[c*8+1]*us2f(w0.y)
                 + s.hvs[c*8+2]*us2f(w0.z) + s.hvs[c*8+3]*us2f(w0.w)
                 + s.hvs[c*8+4]*us2f(w1.x) + s.hvs[c*8+5]*us2f(w1.y)
                 + s.hvs[c*8+6]*us2f(w1.z) + s.hvs[c*8+7]*us2f(w1.w);
        }
        s.spl[tid] = acc;
    }
    __syncthreads();

    if (tid < 24) {
        pl[n*24+tid] = s.spl[tid];
        int p = tid/3, c = tid - p*3;
        float g = s.sR[c*3+0]*s.spl[p*3+0] + s.sR[c*3+1]*s.spl[p*3+1]
                + s.sR[c*3+2]*s.spl[p*3+2] + s.st[c];
        pg[n*24+tid] = g;
    }
    if (tid < 9) Rw[n*9+tid] = s.sR[tid];
    if (tid < 3) tw[n*3+tid] = s.st[tid];
    if (tid < 8) {
        float a=s.spl[tid*3], b=s.spl[tid*3+1], c=s.spl[tid*3+2];
        pln[n*8+tid] = sqrtf(a*a+b*b+c*c + 1e-8f);
    }
}

__global__ __launch_bounds__(64) void prep_k(
    const void* __restrict__ hV, const void* __restrict__ X,
    const unsigned short* __restrict__ wpT, const void* __restrict__ bp,
    float* __restrict__ pg, float* __restrict__ pl, float* __restrict__ pln,
    float* __restrict__ Rw, float* __restrict__ tw, const void* __restrict__ maskV)
{
    __shared__ PrepSmem s;
    int n = blockIdx.x, tid = threadIdx.x;
    if (is_f32(maskV)) prep_body<true >(hV,X,wpT,bp,pg,pl,pln,Rw,tw,s,n,tid);
    else               prep_body<false>(hV,X,wpT,bp,pg,pl,pln,Rw,tw,s,n,tid);
}

// ---------------------------------------------------------------------------
// Kernel B1: edge-MLP. 2 nodes/block, 128 threads = 2 waves (wave = n-half).
//   Layer-1 K-loop now 7 chunks (4 hE + 3 geo), fully unrolled; the own-hV
//   and gathered-neighbor-hV matmul blocks are hoisted into uv_k: their
//   contribution U'[n] + V[j] is gathered as fp32 scalars right after bar0
//   (issued early, completes under the geometry pass) and added at the
//   m1-write epilogue. Wave 0 streams hE back out during the hE chunks.
// ---------------------------------------------------------------------------
#define ASTRIDE 40    // 32 + 8 pad (80B rows, 16B-aligned)
#define MSTRIDE 136   // 128 + 8 pad (272B rows, 16B-aligned)

struct __align__(16) Mp1Smem {
    union __align__(16) {
        unsigned short geo[3][64*ASTRIDE];   // 15.4 KB, dead after layer-1
        unsigned short m[64*MSTRIDE];        // 17.4 KB slab: m1 then m2
    } u;
    int   sj[64];        // per edge-row: global neighbor node index
    float smka[64];      // per edge-row mask
    float spg[2][24], spl[2][24], spln[2][8], sR[2][9], st3[2][3];
};

template<bool F32>
DEV void mpnn1_body(
    const void* hV, const void* hE, const void* maskA,
    const void* bm2, const void* bm3, const int* Eidx,
    const float* pg, const float* pl, const float* pln,
    const float* Rw, const float* tw,
    const unsigned short* wt1, const unsigned short* wt2, const unsigned short* wt3,
    const float* Uw, const float* Vw,
    float* nodemsg, void* outE, Mp1Smem& sm, int n0, int tid)
{
    const int lane = tid & 63, w = tid >> 6;     // w = n-half (0/1)
    const int lm = lane & 15, quad = lane >> 4;

    // ---- stage 0
    if (tid < 64) { int l = tid >> 5;
        sm.sj[tid] = (((n0+l) >> 9) << 9) + Eidx[(long)(n0+l)*32 + (tid & 31)];
    } else { int t = tid - 64; int l = t >> 5;
        sm.smka[t] = ldf<F32>(maskA, (long)(n0+l)*32 + (t & 31));
    }
    if (tid < 48)        { sm.spg[tid/24][tid%24] = pg[(n0+tid/24)*24 + tid%24]; }
    else if (tid < 96)   { int t=tid-48; sm.spl[t/24][t%24] = pl[(n0+t/24)*24 + t%24]; }
    else if (tid < 112)  { int t=tid-96; sm.spln[t>>3][t&7]  = pln[(n0+(t>>3))*8 + (t&7)]; }
    if (tid < 18)        { sm.sR[tid/9][tid%9] = Rw[(n0+tid/9)*9 + tid%9]; }
    else if (tid < 24)   { int t=tid-18; sm.st3[t/3][t%3] = tw[(n0+t/3)*3 + t%3]; }
    __syncthreads();                                   // bar0

    // ---- gather hoisted layer-1 partials: U'[node] + V[neighbor].
    //   Issued here so the (L2-resident) scattered loads complete under the
    //   geometry pass. vg addressing matches the m1-write epilogue exactly.
    float vg[4][4][4];   // [mt][r][nt]
    float ug[2][4];      // [node-half][nt]
    #pragma unroll
    for (int mt=0; mt<4; ++mt)
        #pragma unroll
        for (int r=0; r<4; ++r) {
            int j = sm.sj[16*mt + quad*4 + r];
            #pragma unroll
            for (int nt=0; nt<4; ++nt)
                vg[mt][r][nt] = Vw[(long)j*128 + 64*w + nt*16 + lm];
        }
    #pragma unroll
    for (int nd=0; nd<2; ++nd)
        #pragma unroll
        for (int nt=0; nt<4; ++nt)
            ug[nd][nt] = Uw[(long)(n0+nd)*128 + 64*w + nt*16 + lm];

    // ---- geo chunks (k=384..479), 512 (row,p) tasks over 128 threads
    #pragma unroll
    for (int pass=0; pass<4; ++pass) {
        int v = tid + pass*128;
        int row = v >> 3, p = v & 7, nd = row >> 5;
        int j = sm.sj[row];
        float qx = pg[j*24 + p*3 + 0];
        float qy = pg[j*24 + p*3 + 1];
        float qz = pg[j*24 + p*3 + 2];
        float dx = sm.spg[nd][p*3+0]-qx, dy = sm.spg[nd][p*3+1]-qy, dz = sm.spg[nd][p*3+2]-qz;
        float npg = sqrtf(dx*dx+dy*dy+dz*dz + 1e-8f);
        float ux = qx - sm.st3[nd][0], uy = qy - sm.st3[nd][1], uz = qz - sm.st3[nd][2];
        float l0 = sm.sR[nd][0]*ux + sm.sR[nd][3]*uy + sm.sR[nd][6]*uz;
        float l1 = sm.sR[nd][1]*ux + sm.sR[nd][4]*uy + sm.sR[nd][7]*uz;
        float l2v= sm.sR[nd][2]*ux + sm.sR[nd][5]*uy + sm.sR[nd][8]*uz;
        float npl = sqrtf(l0*l0+l1*l1+l2v*l2v + 1e-8f);
        unsigned short* C0 = sm.u.geo[0];
        unsigned short* C1 = sm.u.geo[1];
        unsigned short* C2 = sm.u.geo[2];
        C0[row*ASTRIDE + p*3+0] = f2us(sm.spl[nd][p*3+0]);
        C0[row*ASTRIDE + p*3+1] = f2us(sm.spl[nd][p*3+1]);
        C0[row*ASTRIDE + p*3+2] = f2us(sm.spl[nd][p*3+2]);
        C0[row*ASTRIDE + 24+p]  = f2us(sm.spln[nd][p]);
        C1[row*ASTRIDE + p*3+0] = f2us(l0);
        C1[row*ASTRIDE + p*3+1] = f2us(l1);
        C1[row*ASTRIDE + p*3+2] = f2us(l2v);
        C1[row*ASTRIDE + 24+p]  = f2us(npl);
        C2[row*ASTRIDE + p]     = f2us(npg);
    }
    for (int z = tid; z < 64*24; z += 128) {
        int row = z / 24, col = 8 + (z % 24);
        sm.u.geo[2][row*ASTRIDE + col] = 0;
    }
    __syncthreads();                                   // bar1

    const unsigned short* wr1[4];
    #pragma unroll
    for (int nt=0; nt<4; ++nt) wr1[nt] = wt1 + (long)(64*w + nt*16 + lm)*480 + quad*8;

    f32x4 acc[4][4];
    {
        f32x4 zv = {0.f,0.f,0.f,0.f};
        #pragma unroll
        for (int mt=0; mt<4; ++mt)
            #pragma unroll
            for (int nt=0; nt<4; ++nt) acc[mt][nt] = zv;
    }

    // ---- layer 1: 4 hE chunks (k=128..255) + 3 geo chunks (k=384..479)
    #pragma unroll
    for (int c=0; c<4; ++c) {
        s16x8 av[4];
        #pragma unroll
        for (int mt=0; mt<4; ++mt) {
            int row16 = 16*mt + lm, nd = mt >> 1;
            long src = ((long)(n0+nd)*32 + (row16&31))*128 + c*32 + quad*8;
            U16x8 pk;
            if (F32) {
                const float4* vp = reinterpret_cast<const float4*>(reinterpret_cast<const float*>(hE) + src);
                float4 x = vp[0], y = vp[1];
                if (w == 0) {
                    float4* d = reinterpret_cast<float4*>(reinterpret_cast<float*>(outE) + src);
                    d[0] = x; d[1] = y;
                }
                pk.u.x = pack2(x.x,x.y); pk.u.y = pack2(x.z,x.w);
                pk.u.z = pack2(y.x,y.y); pk.u.w = pack2(y.z,y.w);
            } else {
                pk.u = *reinterpret_cast<const uint4*>(reinterpret_cast<const unsigned short*>(hE) + src);
                if (w == 0)
                    *reinterpret_cast<uint4*>(reinterpret_cast<unsigned short*>(outE) + src) = pk.u;
            }
            av[mt] = pk.v;
        }
        #pragma unroll
        for (int nt=0; nt<4; ++nt) {
            s16x8 bf = *reinterpret_cast<const s16x8*>(wr1[nt] + (long)(c+4)*32);
            #pragma unroll
            for (int mt=0; mt<4; ++mt)
                acc[mt][nt] = __builtin_amdgcn_mfma_f32_16x16x32_bf16(av[mt], bf, acc[mt][nt], 0,0,0);
        }
    }
    #pragma unroll
    for (int c=0; c<3; ++c) {
        s16x8 av[4];
        #pragma unroll
        for (int mt=0; mt<4; ++mt)
            av[mt] = *reinterpret_cast<const s16x8*>(&sm.u.geo[c][(16*mt+lm)*ASTRIDE + quad*8]);
        #pragma unroll
        for (int nt=0; nt<4; ++nt) {
            s16x8 bf = *reinterpret_cast<const s16x8*>(wr1[nt] + (long)(c+12)*32);
            #pragma unroll
            for (int mt=0; mt<4; ++mt)
                acc[mt][nt] = __builtin_amdgcn_mfma_f32_16x16x32_bf16(av[mt], bf, acc[mt][nt], 0,0,0);
        }
    }
    __syncthreads();                                   // bar2 (geo dead)

    // ---- m1 write (add hoisted U'+V partials, relu)
    #pragma unroll
    for (int mt=0; mt<4; ++mt)
        #pragma unroll
        for (int nt=0; nt<4; ++nt)
            #pragma unroll
            for (int r=0; r<4; ++r)
                sm.u.m[(16*mt + quad*4 + r)*MSTRIDE + 64*w + nt*16 + lm]
                    = f2us(fmaxf(acc[mt][nt][r] + ug[mt>>1][nt] + vg[mt][r][nt], 0.f));
    __syncthreads();                                   // bar3 (m1 ready)

    // ---- layer 2
    #pragma unroll
    for (int nt=0; nt<4; ++nt) {
        float b0 = ldf<F32>(bm2, 64*w + nt*16 + lm);
        f32x4 iv = {b0,b0,b0,b0};
        #pragma unroll
        for (int mt=0; mt<4; ++mt) acc[mt][nt] = iv;
    }
    #pragma unroll
    for (int kc=0; kc<4; ++kc) {
        s16x8 av[4];
        #pragma unroll
        for (int mt=0; mt<4; ++mt)
            av[mt] = *reinterpret_cast<const s16x8*>(&sm.u.m[(16*mt+lm)*MSTRIDE + kc*32 + quad*8]);
        #pragma unroll
        for (int nt=0; nt<4; ++nt) {
            s16x8 bf = *reinterpret_cast<const s16x8*>(&wt2[(long)(64*w + nt*16 + lm)*128 + kc*32 + quad*8]);
            #pragma unroll
            for (int mt=0; mt<4; ++mt)
                acc[mt][nt] = __builtin_amdgcn_mfma_f32_16x16x32_bf16(av[mt], bf, acc[mt][nt], 0,0,0);
        }
    }
    __syncthreads();                                   // bar4 (m1 reads done)

    #pragma unroll
    for (int mt=0; mt<4; ++mt)
        #pragma unroll
        for (int nt=0; nt<4; ++nt)
            #pragma unroll
            for (int r=0; r<4; ++r)
                sm.u.m[(16*mt + quad*4 + r)*MSTRIDE + 64*w + nt*16 + lm]
                    = f2us(fmaxf(acc[mt][nt][r], 0.f));
    __syncthreads();                                   // bar5 (m2 ready)

    // ---- layer 3
    #pragma unroll
    for (int nt=0; nt<4; ++nt) {
        float b0 = ldf<F32>(bm3, 64*w + nt*16 + lm);
        f32x4 iv = {b0,b0,b0,b0};
        #pragma unroll
        for (int mt=0; mt<4; ++mt) acc[mt][nt] = iv;
    }
    #pragma unroll
    for (int kc=0; kc<4; ++kc) {
        s16x8 av[4];
        #pragma unroll
        for (int mt=0; mt<4; ++mt)
            av[mt] = *reinterpret_cast<const s16x8*>(&sm.u.m[(16*mt+lm)*MSTRIDE + kc*32 + quad*8]);
        #pragma unroll
        for (int nt=0; nt<4; ++nt) {
            s16x8 bf = *reinterpret_cast<const s16x8*>(&wt3[(long)(64*w + nt*16 + lm)*128 + kc*32 + quad*8]);
            #pragma unroll
            for (int mt=0; mt<4; ++mt)
                acc[mt][nt] = __builtin_amdgcn_mfma_f32_16x16x32_bf16(av[mt], bf, acc[mt][nt], 0,0,0);
        }
    }

    // ---- masked sum over each node's 32 edges (no barrier needed)
    #pragma unroll
    for (int nt=0; nt<4; ++nt) {
        float s0 = 0.f, s1 = 0.f;
        #pragma unroll
        for (int r=0; r<4; ++r) {
            s0 += acc[0][nt][r] * sm.smka[     quad*4 + r]
                + acc[1][nt][r] * sm.smka[16 + quad*4 + r];
            s1 += acc[2][nt][r] * sm.smka[32 + quad*4 + r]
                + acc[3][nt][r] * sm.smka[48 + quad*4 + r];
        }
        s0 += __shfl_xor(s0, 16); s0 += __shfl_xor(s0, 32);
        s1 += __shfl_xor(s1, 16); s1 += __shfl_xor(s1, 32);
        if (lane < 16) {
            nodemsg[(long)(n0  )*128 + 64*w + nt*16 + lane] = s0;
            nodemsg[(long)(n0+1)*128 + 64*w + nt*16 + lane] = s1;
        }
    }
}

__global__ __launch_bounds__(128) void mpnn1_k(
    const void* __restrict__ hV, const void* __restrict__ hE,
    const void* __restrict__ maskV, const void* __restrict__ maskA,
    const void* __restrict__ bm2, const void* __restrict__ bm3,
    const int* __restrict__ Eidx,
    const float* __restrict__ pg, const float* __restrict__ pl,
    const float* __restrict__ pln, const float* __restrict__ Rw,
    const float* __restrict__ tw,
    const unsigned short* __restrict__ wt1, const unsigned short* __restrict__ wt2,
    const unsigned short* __restrict__ wt3,
    const float* __restrict__ Uw, const float* __restrict__ Vw,
    float* __restrict__ nodemsg, void* __restrict__ dout)
{
    __shared__ Mp1Smem sm;
    int n0 = blockIdx.x * 2, tid = threadIdx.x;
    if (is_f32(maskV)) {
        void* outE = reinterpret_cast<float*>(dout) + 524288;
        mpnn1_body<true >(hV,hE,maskA,bm2,bm3,Eidx,pg,pl,pln,Rw,tw,wt1,wt2,wt3,Uw,Vw,nodemsg,outE,sm,n0,tid);
    } else {
        void* outE = reinterpret_cast<unsigned short*>(dout) + 524288;
        mpnn1_body<false>(hV,hE,maskA,bm2,bm3,Eidx,pg,pl,pln,Rw,tw,wt1,wt2,wt3,Uw,Vw,nodemsg,outE,sm,n0,tid);
    }
}

// ---------------------------------------------------------------------------
// Kernel B2: node FFN. 32 nodes/block, 128 blocks, 256 threads = 4 waves.
//   wave w: m-tile mt=w>>1 (16 rows), n-half h=w&1.
// ---------------------------------------------------------------------------
#define TSTRIDE 520   // 512 + 8 pad

struct __align__(16) FfnSmem {
    unsigned short x1[32*MSTRIDE];                    // 8.7 KB (LN1 out, bf16)
    union __align__(16) {
        unsigned short t1[32*TSTRIDE];                // 33.3 KB hidden (bf16)
        float yf[32*132];                             // 16.9 KB pre-LN2 (fp32)
    } u;
};

template<bool F32>
DEV void ffn_body(const void* hV, const void* maskV, const float* nodemsg,
                  const void* g1, const void* be1, const void* bd1, const void* bd2,
                  const void* g2, const void* be2,
                  const unsigned short* wd1T, const unsigned short* wd2T,
                  void* out, FfnSmem& sm, int n0, int tid)
{
    const int lane = tid & 63, w = tid >> 6;
    const int mt = w >> 1, h = w & 1;
    const int lm = lane & 15, quad = lane >> 4;

    // ---- x = hV + nodemsg/32 ; LN1 -> x1 (bf16). thread: row r, 16 cols.
    {
        const int r = tid >> 3, c0 = (tid & 7) * 16;
        const long nb = (long)(n0 + r)*128;
        float xv[16];
        float s1 = 0.f, s2 = 0.f;
        #pragma unroll
        for (int j=0; j<16; ++j) {
            float v = ldf<F32>(hV, nb + c0 + j) + nodemsg[nb + c0 + j] * (1.f/32.f);
            xv[j] = v; s1 += v; s2 += v*v;
        }
        s1 += __shfl_xor(s1,1); s1 += __shfl_xor(s1,2); s1 += __shfl_xor(s1,4);
        s2 += __shfl_xor(s2,1); s2 += __shfl_xor(s2,2); s2 += __shfl_xor(s2,4);
        float mu = s1 * (1.f/128.f);
        float var = s2 * (1.f/128.f) - mu*mu;
        float rs = 1.f/sqrtf(var + 1e-5f);
        #pragma unroll
        for (int j=0; j<16; ++j) {
            int c = c0 + j;
            sm.x1[r*MSTRIDE + c] = f2us((xv[j]-mu)*rs*ldf<F32>(g1, c) + ldf<F32>(be1, c));
        }
    }
    __syncthreads();

    // ---- d1: 128 -> 512 (wave: 16 rows x 256 cols), relu -> t1
    {
        f32x4 t1a[16];
        #pragma unroll
        for (int nt=0; nt<16; ++nt) {
            float b0 = ldf<F32>(bd1, 256*h + nt*16 + lm);
            f32x4 iv = {b0,b0,b0,b0};
            t1a[nt] = iv;
        }
        #pragma unroll
        for (int kc=0; kc<4; ++kc) {
            s16x8 a = *reinterpret_cast<const s16x8*>(&sm.x1[(16*mt+lm)*MSTRIDE + kc*32 + quad*8]);
            #pragma unroll
            for (int nt=0; nt<16; ++nt) {
                s16x8 bf = *reinterpret_cast<const s16x8*>(&wd1T[(long)(256*h + nt*16 + lm)*128 + kc*32 + quad*8]);
                t1a[nt] = __builtin_amdgcn_mfma_f32_16x16x32_bf16(a, bf, t1a[nt], 0,0,0);
            }
        }
        #pragma unroll
        for (int nt=0; nt<16; ++nt)
            #pragma unroll
            for (int r=0; r<4; ++r)
                sm.u.t1[(16*mt + quad*4 + r)*TSTRIDE + 256*h + nt*16 + lm] = f2us(fmaxf(t1a[nt][r], 0.f));
    }
    __syncthreads();

    // ---- d2: 512 -> 128 (wave: 16 rows x 64 cols)
    f32x4 yacc[4];
    #pragma unroll
    for (int nt=0; nt<4; ++nt) {
        float b0 = ldf<F32>(bd2, 64*h + nt*16 + lm);
        f32x4 iv = {b0,b0,b0,b0};
        yacc[nt] = iv;
    }
    #pragma unroll
    for (int kc=0; kc<16; ++kc) {
        s16x8 a = *reinterpret_cast<const s16x8*>(&sm.u.t1[(16*mt+lm)*TSTRIDE + kc*32 + quad*8]);
        #pragma unroll
        for (int nt=0; nt<4; ++nt) {
            s16x8 bf = *reinterpret_cast<const s16x8*>(&wd2T[(long)(64*h + nt*16 + lm)*512 + kc*32 + quad*8]);
            yacc[nt] = __builtin_amdgcn_mfma_f32_16x16x32_bf16(a, bf, yacc[nt], 0,0,0);
        }
    }
    __syncthreads();   // t1 reads done before yf (alias) writes

    #pragma unroll
    for (int nt=0; nt<4; ++nt)
        #pragma unroll
        for (int r=0; r<4; ++r) {
            int rr = 16*mt + quad*4 + r, c = 64*h + nt*16 + lm;
            sm.u.yf[rr*132 + c] = yacc[nt][r] + us2f(sm.x1[rr*MSTRIDE + c]);
        }
    __syncthreads();

    // ---- LN2 + mask + store
    {
        const int r = tid >> 3, c0 = (tid & 7) * 16;
        float yv[16];
        float s1 = 0.f, s2 = 0.f;
        #pragma unroll
        for (int j=0; j<16; ++j) {
            float v = sm.u.yf[r*132 + c0 + j];
            yv[j] = v; s1 += v; s2 += v*v;
        }
        s1 += __shfl_xor(s1,1); s1 += __shfl_xor(s1,2); s1 += __shfl_xor(s1,4);
        s2 += __shfl_xor(s2,1); s2 += __shfl_xor(s2,2); s2 += __shfl_xor(s2,4);
        float mu = s1 * (1.f/128.f);
        float var = s2 * (1.f/128.f) - mu*mu;
        float rs = 1.f/sqrtf(var + 1e-5f);
        float mv = ldf<F32>(maskV, n0 + r);
        const long ob = (long)(n0 + r)*128 + c0;
        #pragma unroll
        for (int j=0; j<16; ++j) {
            int c = c0 + j;
            float v = ((yv[j]-mu)*rs*ldf<F32>(g2, c) + ldf<F32>(be2, c)) * mv;
            if (F32) reinterpret_cast<float*>(out)[ob + j] = v;
            else     reinterpret_cast<unsigned short*>(out)[ob + j] = f2us(v);
        }
    }
}

__global__ __launch_bounds__(256) void ffn_k(
    const void* __restrict__ hV, const void* __restrict__ maskV,
    const float* __restrict__ nodemsg,
    const void* __restrict__ g1, const void* __restrict__ be1,
    const void* __restrict__ bd1, const void* __restrict__ bd2,
    const void* __restrict__ g2, const void* __restrict__ be2,
    const unsigned short* __restrict__ wd1T, const unsigned short* __restrict__ wd2T,
    void* __restrict__ out)
{
    __shared__ FfnSmem sm;
    int n0 = blockIdx.x * 32, tid = threadIdx.x;
    if (is_f32(maskV))
        ffn_body<true >(hV,maskV,nodemsg,g1,be1,bd1,bd2,g2,be2,wd1T,wd2T,out,sm,n0,tid);
    else
        ffn_body<false>(hV,maskV,nodemsg,g1,be1,bd1,bd2,g2,be2,wd1T,wd2T,out,sm,n0,tid);
}

// ---------------------------------------------------------------------------
extern "C" void kernel_launch(void* const* d_in, const int* in_sizes, int n_in,
                              void* d_out, int out_size, void* d_ws, size_t ws_size,
                              hipStream_t stream)
{
    const void* hV    = d_in[0];
    const void* hE    = d_in[1];
    const void* X     = d_in[2];
    const void* maskV = d_in[3];
    const void* maskA = d_in[4];
    const void* Wp    = d_in[5];
    const void* bp    = d_in[6];
    const void* Wm1   = d_in[7];
    const void* bm1   = d_in[8];
    const void* Wm2   = d_in[9];
    const void* bm2   = d_in[10];
    const void* Wm3   = d_in[11];
    const void* bm3   = d_in[12];
    const void* g1    = d_in[13];
    const void* be1   = d_in[14];
    const void* Wd1   = d_in[15];
    const void* bd1   = d_in[16];
    const void* Wd2   = d_in[17];
    const void* bd2   = d_in[18];
    const void* g2    = d_in[19];
    const void* be2   = d_in[20];
    const int*  Eidx  = (const int*)d_in[21];

    float* ws = (float*)d_ws;
    float* pg  = ws;                 // 98304
    float* pl  = ws + 98304;         // 98304
    float* pln = ws + 196608;        // 32768
    float* Rw  = ws + 229376;        // 36864
    float* tw  = ws + 266240;        // 12288
    float* nm  = ws + 278528;        // 524288
    unsigned short* wt1  = (unsigned short*)(ws + 802816);  // 61440 us
    unsigned short* wt2  = wt1 + 61440;                     // 16384 us
    unsigned short* wt3  = wt2 + 16384;                     // 16384 us
    unsigned short* wpT  = wt3 + 16384;                     // 3072 us
    unsigned short* wd1T = wpT + 3072;                      // 65536 us
    unsigned short* wd2T = wd1T + 65536;                    // 65536 us
    float* Uw = ws + 917504;         // 524288 fp32 (U' = hV@W1a + bm1)
    float* Vw = Uw + 524288;         // 524288 fp32 (V  = hV@W1c)

    wtrans_k<<<892, 256, 0, stream>>>(Wm1, Wm2, Wm3, Wp, Wd1, Wd2,
                                      wt1, wt2, wt3, wpT, wd1T, wd2T, maskV);

    uv_k<<<256, 128, 0, stream>>>(hV, bm1, wt1, Uw, Vw, maskV);

    prep_k<<<4096, 64, 0, stream>>>(hV, X, wpT, bp, pg, pl, pln, Rw, tw, maskV);

    mpnn1_k<<<2048, 128, 0, stream>>>(hV, hE, maskV, maskA, bm2, bm3, Eidx,
                                      pg, pl, pln, Rw, tw, wt1, wt2, wt3,
                                      Uw, Vw, nm, d_out);

    ffn_k<<<128, 256, 0, stream>>>(hV, maskV, nm, g1, be1, bd1, bd2, g2, be2,
                                   wd1T, wd2T, d_out);
}

// Round 2
// 245.012 us; speedup vs baseline: 1.1332x; 1.1017x over previous
//
#include <hip/hip_runtime.h>
#include <hip/hip_bf16.h>

typedef __hip_bfloat16 bf16;
typedef __attribute__((ext_vector_type(8))) short s16x8;
typedef __attribute__((ext_vector_type(4))) float f32x4;

#define DEV __device__ __forceinline__

DEV float us2f(unsigned short u){ return __uint_as_float(((unsigned int)u) << 16); }
DEV unsigned short f2us(float f){
    __hip_bfloat16 h = __float2bfloat16(f);
    unsigned short r; __builtin_memcpy(&r, &h, 2); return r;
}
DEV unsigned pack2(float a, float b){ return (unsigned)f2us(a) | ((unsigned)f2us(b) << 16); }

template<bool F32> DEV float ldf(const void* p, long i){
    if (F32) return reinterpret_cast<const float*>(p)[i];
    return us2f(reinterpret_cast<const unsigned short*>(p)[i]);
}
template<bool F32> DEV unsigned short ld16(const void* p, long i){
    if (F32) return f2us(reinterpret_cast<const float*>(p)[i]);
    return reinterpret_cast<const unsigned short*>(p)[i];
}

union U16x8 { uint4 u; s16x8 v; };

// dtype flag: maskV[0]==1.0 always. bf16 -> ushort0 = 0x3F80; fp32 LE -> 0x0000.
DEV bool is_f32(const void* maskV){
    return reinterpret_cast<const unsigned short*>(maskV)[0] != 0x3F80;
}

// ---------------------------------------------------------------------------
// Kernel P (fused prologue): one launch, three roles by blockIdx:
//   [0,2048)    prep: frames + local/global points (2 nodes/block, own Wp
//               transpose staged in LDS -> no wtrans dependency)
//   [2048,2304) uv:   U'[n]=hV@Wm1[0:128]+bm1, V[n]=hV@Wm1[256:384] -> bf16.
//               Own Wm1 tile-transpose in LDS (32k x 128c per pass).
//   [2304,4064) wtrans: wt1/wt2/wt3/wd1T/wd2T pre-transposes.
// ---------------------------------------------------------------------------
struct __align__(16) PreSmem {
    union __align__(16) {
        unsigned short lwT[128*40];                   // uv: [col][k] 10240 B
        struct {
            unsigned short lwp[24*132];               // prep: WpT, 6336 B
            float sX[2][9], sR[2][9], st3[2][3], spl[2][24], hvs[2][128];
        } pr;
    } u;
};

template<bool F32>
DEV void pre_prep(const void* hV, const void* X, const void* Wp, const void* bp,
                  float* pg, float* pl, float* pln, float* Rw, float* tw,
                  PreSmem& s, int bid, int tid)
{
    auto& pr = s.u.pr;
    // stage Wp transposed: lwp[j][i] = Wp[i][j]  (128 x 24)
    for (int e = tid; e < 3072; e += 128) {
        int i = e / 24, j = e - i*24;
        pr.lwp[j*132 + i] = ld16<F32>(Wp, e);
    }
    const int wv = tid >> 6, ln = tid & 63;
    const int n = bid*2 + wv;
    if (ln < 9) pr.sX[wv][ln] = ldf<F32>(X, (long)n*9 + ln);
    for (int i = ln; i < 128; i += 64) pr.hvs[wv][i] = ldf<F32>(hV, (long)n*128 + i);
    __syncthreads();

    if (ln == 0) {
        float Nx=pr.sX[wv][0],Ny=pr.sX[wv][1],Nz=pr.sX[wv][2];
        float Ax=pr.sX[wv][3],Ay=pr.sX[wv][4],Az=pr.sX[wv][5];
        float Cx=pr.sX[wv][6],Cy=pr.sX[wv][7],Cz=pr.sX[wv][8];
        float v1x=Cx-Ax, v1y=Cy-Ay, v1z=Cz-Az;
        float v2x=Nx-Ax, v2y=Ny-Ay, v2z=Nz-Az;
        float r1 = 1.f/sqrtf(v1x*v1x+v1y*v1y+v1z*v1z + 1e-8f);
        float e1x=v1x*r1, e1y=v1y*r1, e1z=v1z*r1;
        float dp = e1x*v2x+e1y*v2y+e1z*v2z;
        float u2x=v2x-e1x*dp, u2y=v2y-e1y*dp, u2z=v2z-e1z*dp;
        float r2 = 1.f/sqrtf(u2x*u2x+u2y*u2y+u2z*u2z + 1e-8f);
        float e2x=u2x*r2, e2y=u2y*r2, e2z=u2z*r2;
        float e3x = e1y*e2z - e1z*e2y;
        float e3y = e1z*e2x - e1x*e2z;
        float e3z = e1x*e2y - e1y*e2x;
        pr.sR[wv][0]=e1x; pr.sR[wv][1]=e2x; pr.sR[wv][2]=e3x;
        pr.sR[wv][3]=e1y; pr.sR[wv][4]=e2y; pr.sR[wv][5]=e3y;
        pr.sR[wv][6]=e1z; pr.sR[wv][7]=e2z; pr.sR[wv][8]=e3z;
        pr.st3[wv][0]=Ax*0.1f; pr.st3[wv][1]=Ay*0.1f; pr.st3[wv][2]=Az*0.1f;
    }
    if (ln < 24) {
        float acc = ldf<F32>(bp, ln);
        const unsigned short* wr = &pr.lwp[ln*132];
        #pragma unroll
        for (int c=0;c<16;c++){
            #pragma unroll
            for (int k=0;k<8;k++)
                acc += pr.hvs[wv][c*8+k] * us2f(wr[c*8+k]);
        }
        pr.spl[wv][ln] = acc;
    }
    __syncthreads();

    if (ln < 24) {
        pl[n*24+ln] = pr.spl[wv][ln];
        int p = ln/3, c = ln - p*3;
        float g = pr.sR[wv][c*3+0]*pr.spl[wv][p*3+0] + pr.sR[wv][c*3+1]*pr.spl[wv][p*3+1]
                + pr.sR[wv][c*3+2]*pr.spl[wv][p*3+2] + pr.st3[wv][c];
        pg[n*24+ln] = g;
    }
    if (ln < 9) Rw[n*9+ln] = pr.sR[wv][ln];
    if (ln < 3) tw[n*3+ln] = pr.st3[wv][ln];
    if (ln < 8) {
        float a=pr.spl[wv][ln*3], b=pr.spl[wv][ln*3+1], c=pr.spl[wv][ln*3+2];
        pln[n*8+ln] = sqrtf(a*a+b*b+c*c + 1e-8f);
    }
}

template<bool F32>
DEV void pre_uv(const void* hV, const void* bm1, const void* Wm1,
                unsigned short* Uw, unsigned short* Vw,
                PreSmem& s, int r0, int tid)
{
    const int lane = tid & 63, w2 = tid >> 6;        // w2 = col-half
    const int lm = lane & 15, quad = lane >> 4;

    // A-fragments: hV rows r0..r0+15, all 128 k
    s16x8 af[4];
    #pragma unroll
    for (int kc=0; kc<4; ++kc) {
        long src = (long)(r0 + lm)*128 + kc*32 + quad*8;
        U16x8 pk;
        if (F32) {
            const float4* vp = reinterpret_cast<const float4*>(reinterpret_cast<const float*>(hV) + src);
            float4 x = vp[0], y = vp[1];
            pk.u.x = pack2(x.x,x.y); pk.u.y = pack2(x.z,x.w);
            pk.u.z = pack2(y.x,y.y); pk.u.w = pack2(y.z,y.w);
        } else {
            pk.u = *reinterpret_cast<const uint4*>(reinterpret_cast<const unsigned short*>(hV) + src);
        }
        af[kc] = pk.v;
    }

    f32x4 accU[4], accV[4];
    #pragma unroll
    for (int nt=0; nt<4; ++nt) {
        float b0 = ldf<F32>(bm1, 64*w2 + nt*16 + lm);
        f32x4 iv = {b0,b0,b0,b0};
        accU[nt] = iv;
        f32x4 zv = {0.f,0.f,0.f,0.f};
        accV[nt] = zv;
    }

    // 8 passes: p<4 -> Wm1 rows [p*32,+32) for U; p>=4 -> rows [256+(p-4)*32,+32) for V
    for (int p=0; p<8; ++p) {
        int k0 = (p<4) ? p*32 : 256 + (p-4)*32;
        __syncthreads();
        for (int e = tid; e < 4096; e += 128) {
            int kk = e >> 7, c = e & 127;
            s.u.lwT[c*40 + kk] = ld16<F32>(Wm1, (long)k0*128 + e);
        }
        __syncthreads();
        s16x8 a = af[p & 3];
        #pragma unroll
        for (int nt=0; nt<4; ++nt) {
            s16x8 bf = *reinterpret_cast<const s16x8*>(&s.u.lwT[(64*w2 + nt*16 + lm)*40 + quad*8]);
            if (p < 4) accU[nt] = __builtin_amdgcn_mfma_f32_16x16x32_bf16(a, bf, accU[nt], 0,0,0);
            else       accV[nt] = __builtin_amdgcn_mfma_f32_16x16x32_bf16(a, bf, accV[nt], 0,0,0);
        }
    }
    #pragma unroll
    for (int nt=0; nt<4; ++nt)
        #pragma unroll
        for (int r=0; r<4; ++r) {
            long o = (long)(r0 + quad*4 + r)*128 + 64*w2 + nt*16 + lm;
            Uw[o] = f2us(accU[nt][r]);
            Vw[o] = f2us(accV[nt][r]);
        }
}

template<bool F32>
DEV void pre_wt(const void* Wm1, const void* Wm2, const void* Wm3,
                const void* Wd1, const void* Wd2,
                unsigned short* wt1, unsigned short* wt2, unsigned short* wt3,
                unsigned short* wd1T, unsigned short* wd2T, long t)
{
    if (t < 61440) {                 // wt1[h][k] = Wm1[k][h], K padded to 480
        int k = (int)(t >> 7), h = (int)(t & 127);
        wt1[(long)h*480 + k] = (k < 456) ? ld16<F32>(Wm1, (long)k*128 + h) : (unsigned short)0;
    } else if (t < 77824) {
        long t2 = t - 61440; int k = (int)(t2 >> 7), h = (int)(t2 & 127);
        wt2[(long)h*128 + k] = ld16<F32>(Wm2, (long)k*128 + h);
    } else if (t < 94208) {
        long t2 = t - 77824; int k = (int)(t2 >> 7), h = (int)(t2 & 127);
        wt3[(long)h*128 + k] = ld16<F32>(Wm3, (long)k*128 + h);
    } else if (t < 159744) {         // wd1T[n][k] = Wd1[k][n]  (512 x 128)
        long t2 = t - 94208; int k = (int)(t2 >> 9), n = (int)(t2 & 511);
        wd1T[(long)n*128 + k] = ld16<F32>(Wd1, (long)k*512 + n);
    } else {                         // wd2T[n][k] = Wd2[k][n]  (128 x 512)
        long t2 = t - 159744; int k = (int)(t2 >> 7), n = (int)(t2 & 127);
        wd2T[(long)n*512 + k] = ld16<F32>(Wd2, (long)k*128 + n);
    }
}

__global__ __launch_bounds__(128) void pre_k(
    const void* __restrict__ hV, const void* __restrict__ X,
    const void* __restrict__ Wp, const void* __restrict__ bp,
    const void* __restrict__ Wm1, const void* __restrict__ bm1,
    const void* __restrict__ Wm2, const void* __restrict__ Wm3,
    const void* __restrict__ Wd1, const void* __restrict__ Wd2,
    float* __restrict__ pg, float* __restrict__ pl, float* __restrict__ pln,
    float* __restrict__ Rw, float* __restrict__ tw,
    unsigned short* __restrict__ Uw, unsigned short* __restrict__ Vw,
    unsigned short* __restrict__ wt1, unsigned short* __restrict__ wt2,
    unsigned short* __restrict__ wt3, unsigned short* __restrict__ wd1T,
    unsigned short* __restrict__ wd2T, const void* __restrict__ maskV)
{
    __shared__ PreSmem s;
    int bid = blockIdx.x, tid = threadIdx.x;
    bool f32 = is_f32(maskV);
    if (bid < 2048) {
        if (f32) pre_prep<true >(hV,X,Wp,bp,pg,pl,pln,Rw,tw,s,bid,tid);
        else     pre_prep<false>(hV,X,Wp,bp,pg,pl,pln,Rw,tw,s,bid,tid);
    } else if (bid < 2304) {
        int r0 = (bid - 2048) * 16;
        if (f32) pre_uv<true >(hV,bm1,Wm1,Uw,Vw,s,r0,tid);
        else     pre_uv<false>(hV,bm1,Wm1,Uw,Vw,s,r0,tid);
    } else {
        long t = (long)(bid - 2304)*128 + tid;
        if (f32) pre_wt<true >(Wm1,Wm2,Wm3,Wd1,Wd2,wt1,wt2,wt3,wd1T,wd2T,t);
        else     pre_wt<false>(Wm1,Wm2,Wm3,Wd1,Wd2,wt1,wt2,wt3,wd1T,wd2T,t);
    }
}

// ---------------------------------------------------------------------------
// Kernel B1: edge-MLP. 2 nodes/block, 128 threads = 2 waves (wave = n-half).
//   Layer-1: 7 unrolled chunks (4 hE + 3 geo), zero-init acc. The hoisted
//   U'[n]+V[j] partials are added in an LDS read-modify-relu pass after the
//   raw acc write: U rows staged to LDS at bar0; V rows loaded as 8 coalesced
//   16B bf16 loads per thread (no 64-reg gather hoard -> occupancy back up).
// ---------------------------------------------------------------------------
#define ASTRIDE 40    // 32 + 8 pad (80B rows, 16B-aligned)
#define MSTRIDE 136   // 128 + 8 pad (272B rows, 16B-aligned)

struct __align__(16) Mp1Smem {
    union __align__(16) {
        unsigned short geo[3][64*ASTRIDE];   // 15.4 KB, dead after layer-1
        unsigned short m[64*MSTRIDE];        // 17.4 KB slab: m1 then m2
    } u;
    int   sj[64];        // per edge-row: global neighbor node index
    float smka[64];      // per edge-row mask
    float spg[2][24], spl[2][24], spln[2][8], sR[2][9], st3[2][3];
    unsigned short sU[2*128];   // U' rows for the 2 nodes (bf16)
};

template<bool F32>
DEV void mpnn1_body(
    const void* hV, const void* hE, const void* maskA,
    const void* bm2, const void* bm3, const int* Eidx,
    const float* pg, const float* pl, const float* pln,
    const float* Rw, const float* tw,
    const unsigned short* wt1, const unsigned short* wt2, const unsigned short* wt3,
    const unsigned short* Uw, const unsigned short* Vw,
    float* nodemsg, void* outE, Mp1Smem& sm, int n0, int tid)
{
    const int lane = tid & 63, w = tid >> 6;     // w = n-half (0/1)
    const int lm = lane & 15, quad = lane >> 4;

    // ---- stage 0
    if (tid < 64) { int l = tid >> 5;
        sm.sj[tid] = (((n0+l) >> 9) << 9) + Eidx[(long)(n0+l)*32 + (tid & 31)];
    } else { int t = tid - 64; int l = t >> 5;
        sm.smka[t] = ldf<F32>(maskA, (long)(n0+l)*32 + (t & 31));
    }
    if (tid < 48)        { sm.spg[tid/24][tid%24] = pg[(n0+tid/24)*24 + tid%24]; }
    else if (tid < 96)   { int t=tid-48; sm.spl[t/24][t%24] = pl[(n0+t/24)*24 + t%24]; }
    else if (tid < 112)  { int t=tid-96; sm.spln[t>>3][t&7]  = pln[(n0+(t>>3))*8 + (t&7)]; }
    if (tid < 18)        { sm.sR[tid/9][tid%9] = Rw[(n0+tid/9)*9 + tid%9]; }
    else if (tid < 24)   { int t=tid-18; sm.st3[t/3][t%3] = tw[(n0+t/3)*3 + t%3]; }
    for (int e = tid; e < 256; e += 128)
        sm.sU[e] = Uw[(long)(n0 + (e>>7))*128 + (e & 127)];
    __syncthreads();                                   // bar0

    // ---- geo chunks (k=384..479), 512 (row,p) tasks over 128 threads
    #pragma unroll
    for (int pass=0; pass<4; ++pass) {
        int v = tid + pass*128;
        int row = v >> 3, p = v & 7, nd = row >> 5;
        int j = sm.sj[row];
        float qx = pg[j*24 + p*3 + 0];
        float qy = pg[j*24 + p*3 + 1];
        float qz = pg[j*24 + p*3 + 2];
        float dx = sm.spg[nd][p*3+0]-qx, dy = sm.spg[nd][p*3+1]-qy, dz = sm.spg[nd][p*3+2]-qz;
        float npg = sqrtf(dx*dx+dy*dy+dz*dz + 1e-8f);
        float ux = qx - sm.st3[nd][0], uy = qy - sm.st3[nd][1], uz = qz - sm.st3[nd][2];
        float l0 = sm.sR[nd][0]*ux + sm.sR[nd][3]*uy + sm.sR[nd][6]*uz;
        float l1 = sm.sR[nd][1]*ux + sm.sR[nd][4]*uy + sm.sR[nd][7]*uz;
        float l2v= sm.sR[nd][2]*ux + sm.sR[nd][5]*uy + sm.sR[nd][8]*uz;
        float npl = sqrtf(l0*l0+l1*l1+l2v*l2v + 1e-8f);
        unsigned short* C0 = sm.u.geo[0];
        unsigned short* C1 = sm.u.geo[1];
        unsigned short* C2 = sm.u.geo[2];
        C0[row*ASTRIDE + p*3+0] = f2us(sm.spl[nd][p*3+0]);
        C0[row*ASTRIDE + p*3+1] = f2us(sm.spl[nd][p*3+1]);
        C0[row*ASTRIDE + p*3+2] = f2us(sm.spl[nd][p*3+2]);
        C0[row*ASTRIDE + 24+p]  = f2us(sm.spln[nd][p]);
        C1[row*ASTRIDE + p*3+0] = f2us(l0);
        C1[row*ASTRIDE + p*3+1] = f2us(l1);
        C1[row*ASTRIDE + p*3+2] = f2us(l2v);
        C1[row*ASTRIDE + 24+p]  = f2us(npl);
        C2[row*ASTRIDE + p]     = f2us(npg);
    }
    for (int z = tid; z < 64*24; z += 128) {
        int row = z / 24, col = 8 + (z % 24);
        sm.u.geo[2][row*ASTRIDE + col] = 0;
    }
    __syncthreads();                                   // bar1

    const unsigned short* wr1[4];
    #pragma unroll
    for (int nt=0; nt<4; ++nt) wr1[nt] = wt1 + (long)(64*w + nt*16 + lm)*480 + quad*8;

    f32x4 acc[4][4];
    {
        f32x4 zv = {0.f,0.f,0.f,0.f};
        #pragma unroll
        for (int mt=0; mt<4; ++mt)
            #pragma unroll
            for (int nt=0; nt<4; ++nt) acc[mt][nt] = zv;
    }

    // ---- layer 1: 4 hE chunks (k=128..255) + 3 geo chunks (k=384..479)
    #pragma unroll
    for (int c=0; c<4; ++c) {
        s16x8 av[4];
        #pragma unroll
        for (int mt=0; mt<4; ++mt) {
            int row16 = 16*mt + lm, nd = mt >> 1;
            long src = ((long)(n0+nd)*32 + (row16&31))*128 + c*32 + quad*8;
            U16x8 pk;
            if (F32) {
                const float4* vp = reinterpret_cast<const float4*>(reinterpret_cast<const float*>(hE) + src);
                float4 x = vp[0], y = vp[1];
                if (w == 0) {
                    float4* d = reinterpret_cast<float4*>(reinterpret_cast<float*>(outE) + src);
                    d[0] = x; d[1] = y;
                }
                pk.u.x = pack2(x.x,x.y); pk.u.y = pack2(x.z,x.w);
                pk.u.z = pack2(y.x,y.y); pk.u.w = pack2(y.z,y.w);
            } else {
                pk.u = *reinterpret_cast<const uint4*>(reinterpret_cast<const unsigned short*>(hE) + src);
                if (w == 0)
                    *reinterpret_cast<uint4*>(reinterpret_cast<unsigned short*>(outE) + src) = pk.u;
            }
            av[mt] = pk.v;
        }
        #pragma unroll
        for (int nt=0; nt<4; ++nt) {
            s16x8 bf = *reinterpret_cast<const s16x8*>(wr1[nt] + (long)(c+4)*32);
            #pragma unroll
            for (int mt=0; mt<4; ++mt)
                acc[mt][nt] = __builtin_amdgcn_mfma_f32_16x16x32_bf16(av[mt], bf, acc[mt][nt], 0,0,0);
        }
    }
    #pragma unroll
    for (int c=0; c<3; ++c) {
        s16x8 av[4];
        #pragma unroll
        for (int mt=0; mt<4; ++mt)
            av[mt] = *reinterpret_cast<const s16x8*>(&sm.u.geo[c][(16*mt+lm)*ASTRIDE + quad*8]);
        #pragma unroll
        for (int nt=0; nt<4; ++nt) {
            s16x8 bf = *reinterpret_cast<const s16x8*>(wr1[nt] + (long)(c+12)*32);
            #pragma unroll
            for (int mt=0; mt<4; ++mt)
                acc[mt][nt] = __builtin_amdgcn_mfma_f32_16x16x32_bf16(av[mt], bf, acc[mt][nt], 0,0,0);
        }
    }
    __syncthreads();                                   // bar2 (geo dead)

    // ---- m1 raw write (acc only, pre-relu, bf16)
    #pragma unroll
    for (int mt=0; mt<4; ++mt)
        #pragma unroll
        for (int nt=0; nt<4; ++nt)
            #pragma unroll
            for (int r=0; r<4; ++r)
                sm.u.m[(16*mt + quad*4 + r)*MSTRIDE + 64*w + nt*16 + lm]
                    = f2us(acc[mt][nt][r]);

    // ---- issue V row loads (coalesced 16B, L2-resident) while writes drain
    const int row = tid >> 1, ch = tid & 1;
    const int jv = sm.sj[row];
    const unsigned short* vrow = Vw + (long)jv*128 + ch*64;
    uint4 pv[8];
    #pragma unroll
    for (int b=0;b<8;++b) pv[b] = *reinterpret_cast<const uint4*>(vrow + b*8);
    __syncthreads();                                   // bar3a

    // ---- m1 += U' + V, relu (in-place LDS RMW)
    {
        unsigned short* mrow = &sm.u.m[row*MSTRIDE + ch*64];
        const unsigned short* urow = &sm.sU[(row>>5)*128 + ch*64];
        #pragma unroll
        for (int b=0;b<8;++b) {
            U16x8 vm; vm.u = *reinterpret_cast<const uint4*>(mrow + b*8);
            U16x8 vv; vv.u = pv[b];
            float f[8];
            #pragma unroll
            for (int i=0;i<8;++i)
                f[i] = fmaxf(us2f((unsigned short)vm.v[i]) + us2f((unsigned short)vv.v[i])
                             + us2f(urow[b*8+i]), 0.f);
            uint4 o;
            o.x = pack2(f[0],f[1]); o.y = pack2(f[2],f[3]);
            o.z = pack2(f[4],f[5]); o.w = pack2(f[6],f[7]);
            *reinterpret_cast<uint4*>(mrow + b*8) = o;
        }
    }
    __syncthreads();                                   // bar3b (m1 ready)

    // ---- layer 2
    #pragma unroll
    for (int nt=0; nt<4; ++nt) {
        float b0 = ldf<F32>(bm2, 64*w + nt*16 + lm);
        f32x4 iv = {b0,b0,b0,b0};
        #pragma unroll
        for (int mt=0; mt<4; ++mt) acc[mt][nt] = iv;
    }
    #pragma unroll
    for (int kc=0; kc<4; ++kc) {
        s16x8 av[4];
        #pragma unroll
        for (int mt=0; mt<4; ++mt)
            av[mt] = *reinterpret_cast<const s16x8*>(&sm.u.m[(16*mt+lm)*MSTRIDE + kc*32 + quad*8]);
        #pragma unroll
        for (int nt=0; nt<4; ++nt) {
            s16x8 bf = *reinterpret_cast<const s16x8*>(&wt2[(long)(64*w + nt*16 + lm)*128 + kc*32 + quad*8]);
            #pragma unroll
            for (int mt=0; mt<4; ++mt)
                acc[mt][nt] = __builtin_amdgcn_mfma_f32_16x16x32_bf16(av[mt], bf, acc[mt][nt], 0,0,0);
        }
    }
    __syncthreads();                                   // bar4 (m1 reads done)

    #pragma unroll
    for (int mt=0; mt<4; ++mt)
        #pragma unroll
        for (int nt=0; nt<4; ++nt)
            #pragma unroll
            for (int r=0; r<4; ++r)
                sm.u.m[(16*mt + quad*4 + r)*MSTRIDE + 64*w + nt*16 + lm]
                    = f2us(fmaxf(acc[mt][nt][r], 0.f));
    __syncthreads();                                   // bar5 (m2 ready)

    // ---- layer 3
    #pragma unroll
    for (int nt=0; nt<4; ++nt) {
        float b0 = ldf<F32>(bm3, 64*w + nt*16 + lm);
        f32x4 iv = {b0,b0,b0,b0};
        #pragma unroll
        for (int mt=0; mt<4; ++mt) acc[mt][nt] = iv;
    }
    #pragma unroll
    for (int kc=0; kc<4; ++kc) {
        s16x8 av[4];
        #pragma unroll
        for (int mt=0; mt<4; ++mt)
            av[mt] = *reinterpret_cast<const s16x8*>(&sm.u.m[(16*mt+lm)*MSTRIDE + kc*32 + quad*8]);
        #pragma unroll
        for (int nt=0; nt<4; ++nt) {
            s16x8 bf = *reinterpret_cast<const s16x8*>(&wt3[(long)(64*w + nt*16 + lm)*128 + kc*32 + quad*8]);
            #pragma unroll
            for (int mt=0; mt<4; ++mt)
                acc[mt][nt] = __builtin_amdgcn_mfma_f32_16x16x32_bf16(av[mt], bf, acc[mt][nt], 0,0,0);
        }
    }

    // ---- masked sum over each node's 32 edges (no barrier needed)
    #pragma unroll
    for (int nt=0; nt<4; ++nt) {
        float s0 = 0.f, s1 = 0.f;
        #pragma unroll
        for (int r=0; r<4; ++r) {
            s0 += acc[0][nt][r] * sm.smka[     quad*4 + r]
                + acc[1][nt][r] * sm.smka[16 + quad*4 + r];
            s1 += acc[2][nt][r] * sm.smka[32 + quad*4 + r]
                + acc[3][nt][r] * sm.smka[48 + quad*4 + r];
        }
        s0 += __shfl_xor(s0, 16); s0 += __shfl_xor(s0, 32);
        s1 += __shfl_xor(s1, 16); s1 += __shfl_xor(s1, 32);
        if (lane < 16) {
            nodemsg[(long)(n0  )*128 + 64*w + nt*16 + lane] = s0;
            nodemsg[(long)(n0+1)*128 + 64*w + nt*16 + lane] = s1;
        }
    }
}

__global__ __launch_bounds__(128) void mpnn1_k(
    const void* __restrict__ hV, const void* __restrict__ hE,
    const void* __restrict__ maskV, const void* __restrict__ maskA,
    const void* __restrict__ bm2, const void* __restrict__ bm3,
    const int* __restrict__ Eidx,
    const float* __restrict__ pg, const float* __restrict__ pl,
    const float* __restrict__ pln, const float* __restrict__ Rw,
    const float* __restrict__ tw,
    const unsigned short* __restrict__ wt1, const unsigned short* __restrict__ wt2,
    const unsigned short* __restrict__ wt3,
    const unsigned short* __restrict__ Uw, const unsigned short* __restrict__ Vw,
    float* __restrict__ nodemsg, void* __restrict__ dout)
{
    __shared__ Mp1Smem sm;
    int n0 = blockIdx.x * 2, tid = threadIdx.x;
    if (is_f32(maskV)) {
        void* outE = reinterpret_cast<float*>(dout) + 524288;
        mpnn1_body<true >(hV,hE,maskA,bm2,bm3,Eidx,pg,pl,pln,Rw,tw,wt1,wt2,wt3,Uw,Vw,nodemsg,outE,sm,n0,tid);
    } else {
        void* outE = reinterpret_cast<unsigned short*>(dout) + 524288;
        mpnn1_body<false>(hV,hE,maskA,bm2,bm3,Eidx,pg,pl,pln,Rw,tw,wt1,wt2,wt3,Uw,Vw,nodemsg,outE,sm,n0,tid);
    }
}

// ---------------------------------------------------------------------------
// Kernel B2: node FFN. 16 nodes/block, 256 blocks (all CUs), 256 threads.
//   d1: wave w -> 16 rows x cols [128w,128w+128). d2: cols [32w,32w+32).
// ---------------------------------------------------------------------------
#define TSTRIDE 520   // 512 + 8 pad

struct __align__(16) FfnSmem {
    unsigned short x1[16*MSTRIDE];                    // 4.4 KB (LN1 out, bf16)
    union __align__(16) {
        unsigned short t1[16*TSTRIDE];                // 16.6 KB hidden (bf16)
        float yf[16*132];                             // 8.4 KB pre-LN2 (fp32)
    } u;
};

template<bool F32>
DEV void ffn_body(const void* hV, const void* maskV, const float* nodemsg,
                  const void* g1, const void* be1, const void* bd1, const void* bd2,
                  const void* g2, const void* be2,
                  const unsigned short* wd1T, const unsigned short* wd2T,
                  void* out, FfnSmem& sm, int n0, int tid)
{
    const int lane = tid & 63, w = tid >> 6;
    const int lm = lane & 15, quad = lane >> 4;

    // ---- x = hV + nodemsg/32 ; LN1 -> x1 (bf16). thread: row r, 8 cols.
    {
        const int r = tid >> 4, c0 = (tid & 15) * 8;
        const long nb = (long)(n0 + r)*128;
        float xv[8];
        float s1 = 0.f, s2 = 0.f;
        #pragma unroll
        for (int j=0; j<8; ++j) {
            float v = ldf<F32>(hV, nb + c0 + j) + nodemsg[nb + c0 + j] * (1.f/32.f);
            xv[j] = v; s1 += v; s2 += v*v;
        }
        s1 += __shfl_xor(s1,1); s1 += __shfl_xor(s1,2);
        s1 += __shfl_xor(s1,4); s1 += __shfl_xor(s1,8);
        s2 += __shfl_xor(s2,1); s2 += __shfl_xor(s2,2);
        s2 += __shfl_xor(s2,4); s2 += __shfl_xor(s2,8);
        float mu = s1 * (1.f/128.f);
        float var = s2 * (1.f/128.f) - mu*mu;
        float rs = 1.f/sqrtf(var + 1e-5f);
        #pragma unroll
        for (int j=0; j<8; ++j) {
            int c = c0 + j;
            sm.x1[r*MSTRIDE + c] = f2us((xv[j]-mu)*rs*ldf<F32>(g1, c) + ldf<F32>(be1, c));
        }
    }
    __syncthreads();

    // ---- d1: 128 -> 512 (wave: 16 rows x 128 cols), relu -> t1
    {
        f32x4 t1a[8];
        #pragma unroll
        for (int nt=0; nt<8; ++nt) {
            float b0 = ldf<F32>(bd1, 128*w + nt*16 + lm);
            f32x4 iv = {b0,b0,b0,b0};
            t1a[nt] = iv;
        }
        #pragma unroll
        for (int kc=0; kc<4; ++kc) {
            s16x8 a = *reinterpret_cast<const s16x8*>(&sm.x1[lm*MSTRIDE + kc*32 + quad*8]);
            #pragma unroll
            for (int nt=0; nt<8; ++nt) {
                s16x8 bf = *reinterpret_cast<const s16x8*>(&wd1T[(long)(128*w + nt*16 + lm)*128 + kc*32 + quad*8]);
                t1a[nt] = __builtin_amdgcn_mfma_f32_16x16x32_bf16(a, bf, t1a[nt], 0,0,0);
            }
        }
        #pragma unroll
        for (int nt=0; nt<8; ++nt)
            #pragma unroll
            for (int r=0; r<4; ++r)
                sm.u.t1[(quad*4 + r)*TSTRIDE + 128*w + nt*16 + lm] = f2us(fmaxf(t1a[nt][r], 0.f));
    }
    __syncthreads();

    // ---- d2: 512 -> 128 (wave: 16 rows x 32 cols)
    f32x4 yacc[2];
    #pragma unroll
    for (int nt=0; nt<2; ++nt) {
        float b0 = ldf<F32>(bd2, 32*w + nt*16 + lm);
        f32x4 iv = {b0,b0,b0,b0};
        yacc[nt] = iv;
    }
    #pragma unroll
    for (int kc=0; kc<16; ++kc) {
        s16x8 a = *reinterpret_cast<const s16x8*>(&sm.u.t1[lm*TSTRIDE + kc*32 + quad*8]);
        #pragma unroll
        for (int nt=0; nt<2; ++nt) {
            s16x8 bf = *reinterpret_cast<const s16x8*>(&wd2T[(long)(32*w + nt*16 + lm)*512 + kc*32 + quad*8]);
            yacc[nt] = __builtin_amdgcn_mfma_f32_16x16x32_bf16(a, bf, yacc[nt], 0,0,0);
        }
    }
    __syncthreads();   // t1 reads done before yf (alias) writes

    #pragma unroll
    for (int nt=0; nt<2; ++nt)
        #pragma unroll
        for (int r=0; r<4; ++r) {
            int rr = quad*4 + r, c = 32*w + nt*16 + lm;
            sm.u.yf[rr*132 + c] = yacc[nt][r] + us2f(sm.x1[rr*MSTRIDE + c]);
        }
    __syncthreads();

    // ---- LN2 + mask + store
    {
        const int r = tid >> 4, c0 = (tid & 15) * 8;
        float yv[8];
        float s1 = 0.f, s2 = 0.f;
        #pragma unroll
        for (int j=0; j<8; ++j) {
            float v = sm.u.yf[r*132 + c0 + j];
            yv[j] = v; s1 += v; s2 += v*v;
        }
        s1 += __shfl_xor(s1,1); s1 += __shfl_xor(s1,2);
        s1 += __shfl_xor(s1,4); s1 += __shfl_xor(s1,8);
        s2 += __shfl_xor(s2,1); s2 += __shfl_xor(s2,2);
        s2 += __shfl_xor(s2,4); s2 += __shfl_xor(s2,8);
        float mu = s1 * (1.f/128.f);
        float var = s2 * (1.f/128.f) - mu*mu;
        float rs = 1.f/sqrtf(var + 1e-5f);
        float mv = ldf<F32>(maskV, n0 + r);
        const long ob = (long)(n0 + r)*128 + c0;
        #pragma unroll
        for (int j=0; j<8; ++j) {
            int c = c0 + j;
            float v = ((yv[j]-mu)*rs*ldf<F32>(g2, c) + ldf<F32>(be2, c)) * mv;
            if (F32) reinterpret_cast<float*>(out)[ob + j] = v;
            else     reinterpret_cast<unsigned short*>(out)[ob + j] = f2us(v);
        }
    }
}

__global__ __launch_bounds__(256) void ffn_k(
    const void* __restrict__ hV, const void* __restrict__ maskV,
    const float* __restrict__ nodemsg,
    const void* __restrict__ g1, const void* __restrict__ be1,
    const void* __restrict__ bd1, const void* __restrict__ bd2,
    const void* __restrict__ g2, const void* __restrict__ be2,
    const unsigned short* __restrict__ wd1T, const unsigned short* __restrict__ wd2T,
    void* __restrict__ out)
{
    __shared__ FfnSmem sm;
    int n0 = blockIdx.x * 16, tid = threadIdx.x;
    if (is_f32(maskV))
        ffn_body<true >(hV,maskV,nodemsg,g1,be1,bd1,bd2,g2,be2,wd1T,wd2T,out,sm,n0,tid);
    else
        ffn_body<false>(hV,maskV,nodemsg,g1,be1,bd1,bd2,g2,be2,wd1T,wd2T,out,sm,n0,tid);
}

// ---------------------------------------------------------------------------
extern "C" void kernel_launch(void* const* d_in, const int* in_sizes, int n_in,
                              void* d_out, int out_size, void* d_ws, size_t ws_size,
                              hipStream_t stream)
{
    const void* hV    = d_in[0];
    const void* hE    = d_in[1];
    const void* X     = d_in[2];
    const void* maskV = d_in[3];
    const void* maskA = d_in[4];
    const void* Wp    = d_in[5];
    const void* bp    = d_in[6];
    const void* Wm1   = d_in[7];
    const void* bm1   = d_in[8];
    const void* Wm2   = d_in[9];
    const void* bm2   = d_in[10];
    const void* Wm3   = d_in[11];
    const void* bm3   = d_in[12];
    const void* g1    = d_in[13];
    const void* be1   = d_in[14];
    const void* Wd1   = d_in[15];
    const void* bd1   = d_in[16];
    const void* Wd2   = d_in[17];
    const void* bd2   = d_in[18];
    const void* g2    = d_in[19];
    const void* be2   = d_in[20];
    const int*  Eidx  = (const int*)d_in[21];

    float* ws = (float*)d_ws;
    float* pg  = ws;                 // 98304
    float* pl  = ws + 98304;         // 98304
    float* pln = ws + 196608;        // 32768
    float* Rw  = ws + 229376;        // 36864
    float* tw  = ws + 266240;        // 12288
    float* nm  = ws + 278528;        // 524288
    unsigned short* wt1  = (unsigned short*)(ws + 802816);  // 61440 us
    unsigned short* wt2  = wt1 + 61440;                     // 16384 us
    unsigned short* wt3  = wt2 + 16384;                     // 16384 us
    unsigned short* wd1T = wt3 + 16384;                     // 65536 us
    unsigned short* wd2T = wd1T + 65536;                    // 65536 us
    unsigned short* Uw   = wd2T + 65536;                    // 524288 us (bf16)
    unsigned short* Vw   = Uw + 524288;                     // 524288 us (bf16)

    pre_k<<<4064, 128, 0, stream>>>(hV, X, Wp, bp, Wm1, bm1, Wm2, Wm3, Wd1, Wd2,
                                    pg, pl, pln, Rw, tw, Uw, Vw,
                                    wt1, wt2, wt3, wd1T, wd2T, maskV);

    mpnn1_k<<<2048, 128, 0, stream>>>(hV, hE, maskV, maskA, bm2, bm3, Eidx,
                                      pg, pl, pln, Rw, tw, wt1, wt2, wt3,
                                      Uw, Vw, nm, d_out);

    ffn_k<<<256, 256, 0, stream>>>(hV, maskV, nm, g1, be1, bd1, bd2, g2, be2,
                                   wd1T, wd2T, d_out);
}